// Round 18
// baseline (116.420 us; speedup 1.0000x reference)
//
#include <hip/hip_runtime.h>

// Triangle attention, B=1, I=J=256, C=128, H=4, Ch=32.
// Round 18: lnproj to 3 blocks/CU — LDS 74.2->53.2KB (sB K-split [128][72],
// k_out3's measured-clean pattern; sWt dropped, tri B-frags from global wtT
// per r10's verified k_prep). Weight halves relayed through registers
// (wreg[4], static idx, +16 VGPR) so no exposed L2 gap at half swaps.
// Store maps/tile identical to r17 (the r8/r10 hazards). attn6d/out3 frozen.
// Fallback: r17 lnproj if WRITE_SIZE balloons or time regresses.
// ws layout (bytes):
//   q     bf16 [I][H][J][32]         @ 16 MB   (pre-scaled Ch^-0.5*log2e)
//   k     bf16 [I][H][J][32]         @ 32 MB
//   vt    bf16 [I][H][32(ch)][J]     @ 48 MB
//   g     bf16 [65536][128]          @ 64 MB   (sigmoid gate)
//   o     bf16 [I][J][H][32]         @ 80 MB   (attention out, PRE-GATED)
//   triTb bf16 [H][256(q)][256(kv)]  @ 96 MB   (512 KB, pre-scaled log2e)
//   wT    bf16 5 x [128(n)][128(k)]  @ 97 MB   (160 KB)
//   wtT   bf16 [16][128]             @ 97 MB + 160 KB  (w_tri^T, rows 4..15=0)

typedef __attribute__((ext_vector_type(4))) float f32x4;
typedef __attribute__((ext_vector_type(8))) short bf16x8;
#define MFMA16(a, b, c) __builtin_amdgcn_mfma_f32_16x16x32_bf16(a, b, c, 0, 0, 0)
#define LOG2E 1.4426950408889634f

__device__ __forceinline__ float bf2f(unsigned int u16) {
    return __uint_as_float(u16 << 16);
}
__device__ __forceinline__ unsigned int f2bf(float f) {
    unsigned int u = __float_as_uint(f);
    return (u + 0x7fffu + ((u >> 16) & 1u)) >> 16;
}
__device__ __forceinline__ unsigned int pack2(float a, float b) {
    return f2bf(a) | (f2bf(b) << 16);
}
__device__ __forceinline__ unsigned int cvt_pk_bf16(float lo, float hi) {
    unsigned int r;
    asm("v_cvt_pk_bf16_f32 %0, %1, %2" : "=v"(r) : "v"(lo), "v"(hi));
    return r;
}
// barrier that drains LDS ops only (global stores keep flowing)
__device__ __forceinline__ void barrier_lgkm() {
    asm volatile("s_waitcnt lgkmcnt(0)" ::: "memory");
    __builtin_amdgcn_s_barrier();
}

// ---------------- Kernel 0: weight transpose + bf16 cast + w_triT ---------
__global__ __launch_bounds__(128) void k_prep(
    const float* __restrict__ wq, const float* __restrict__ wk,
    const float* __restrict__ wv, const float* __restrict__ wg,
    const float* __restrict__ wo, const float* __restrict__ w_tri,
    unsigned short* __restrict__ wT, unsigned short* __restrict__ wtT)
{
    const int mat = blockIdx.x, t = threadIdx.x;
    if (mat == 5) {
        if (blockIdx.y == 0) {
            const float4 wv4 = ((const float4*)w_tri)[t];
            wtT[0 * 128 + t] = (unsigned short)f2bf(wv4.x);
            wtT[1 * 128 + t] = (unsigned short)f2bf(wv4.y);
            wtT[2 * 128 + t] = (unsigned short)f2bf(wv4.z);
            wtT[3 * 128 + t] = (unsigned short)f2bf(wv4.w);
            #pragma unroll
            for (int n = 4; n < 16; ++n) wtT[n * 128 + t] = 0;
        }
        return;
    }
    const int k0 = blockIdx.y * 16;
    const float* W = (mat == 0) ? wq : (mat == 1) ? wk : (mat == 2) ? wv
                     : (mat == 3) ? wg : wo;
    unsigned short* T = wT + mat * 16384;
    float col[16];
    #pragma unroll
    for (int kk = 0; kk < 16; ++kk) col[kk] = W[(k0 + kk) * 128 + t];
    unsigned int pk[8];
    #pragma unroll
    for (int u = 0; u < 8; ++u) pk[u] = pack2(col[2 * u], col[2 * u + 1]);
    *(uint4*)(T + t * 128 + k0)     = make_uint4(pk[0], pk[1], pk[2], pk[3]);
    *(uint4*)(T + t * 128 + k0 + 8) = make_uint4(pk[4], pk[5], pk[6], pk[7]);
}

// -------- Kernel 1: fused LayerNorm + tri bias + q/k/v/g projections ------
// 53.2KB LDS -> 3 blocks/CU; K-split sB with register weight relay.
__global__ __launch_bounds__(256, 3) void k_lnproj(
    const float* __restrict__ x, const float* __restrict__ ln_w,
    const float* __restrict__ ln_b, const unsigned short* __restrict__ wtT,
    const unsigned short* __restrict__ wT, const float* __restrict__ bg,
    unsigned short* __restrict__ qb, unsigned short* __restrict__ kb,
    unsigned short* __restrict__ vtb, unsigned short* __restrict__ gb,
    unsigned short* __restrict__ triTb)
{
    __shared__ unsigned short sA[128 * 136];   // xn tile, then epilogue bounce
    __shared__ unsigned short sB[128 * 72];    // weight K-half

    const int t = threadIdx.x, w = t >> 6, lane = t & 63;
    const int l15 = lane & 15, g = lane >> 4;
    const int rowBase = blockIdx.x * 128;
    const int r2 = t >> 1, half2 = t & 1;

    // ---- LayerNorm: 2 threads per row ----
    {
        const float* xr = x + (size_t)(rowBase + r2) * 128 + half2 * 64;
        float v[64];
        float s1 = 0.0f, s2 = 0.0f;
        #pragma unroll
        for (int u = 0; u < 16; ++u) {
            const float4 q4 = ((const float4*)xr)[u];
            v[4*u] = q4.x; v[4*u+1] = q4.y; v[4*u+2] = q4.z; v[4*u+3] = q4.w;
            s1 += q4.x + q4.y + q4.z + q4.w;
            s2 += q4.x*q4.x + q4.y*q4.y + q4.z*q4.z + q4.w*q4.w;
        }
        s1 += __shfl_xor(s1, 1);
        s2 += __shfl_xor(s2, 1);
        const float mu = s1 * (1.0f / 128.0f);
        const float rs = rsqrtf(s2 * (1.0f / 128.0f) - mu * mu + 1e-5f);
        const float4* lw = (const float4*)(ln_w + half2 * 64);
        const float4* lb = (const float4*)(ln_b + half2 * 64);
        #pragma unroll
        for (int u = 0; u < 16; ++u) {
            const float4 w4 = lw[u], b4 = lb[u];
            v[4*u]   = (v[4*u]   - mu) * rs * w4.x + b4.x;
            v[4*u+1] = (v[4*u+1] - mu) * rs * w4.y + b4.y;
            v[4*u+2] = (v[4*u+2] - mu) * rs * w4.z + b4.z;
            v[4*u+3] = (v[4*u+3] - mu) * rs * w4.w + b4.w;
        }
        #pragma unroll
        for (int u = 0; u < 8; ++u) {
            uint4 pk;
            pk.x = pack2(v[8*u],   v[8*u+1]);
            pk.y = pack2(v[8*u+2], v[8*u+3]);
            pk.z = pack2(v[8*u+4], v[8*u+5]);
            pk.w = pack2(v[8*u+6], v[8*u+7]);
            *(uint4*)&sA[r2 * 136 + half2 * 64 + u * 8] = pk;
        }
    }

    // stage W[0].kc0 into sB (hidden under LN); prefetch W[0].kc1 into regs
    {
        const unsigned short* Wm = wT + r2 * 128 + half2 * 32;
        #pragma unroll
        for (int u = 0; u < 4; ++u)
            *(uint4*)&sB[r2 * 72 + half2 * 32 + u * 8] = *(const uint4*)(Wm + u * 8);
    }
    uint4 wreg[4];
    {
        const unsigned short* p = wT + r2 * 128 + 64 + half2 * 32;
        #pragma unroll
        for (int u = 0; u < 4; ++u) wreg[u] = *(const uint4*)(p + u * 8);
    }
    __syncthreads();   // full barrier once: sA + sB(w0.kc0) ready

    bf16x8 af[2][4];
    #pragma unroll
    for (int m = 0; m < 2; ++m)
        #pragma unroll
        for (int ks = 0; ks < 4; ++ks)
            af[m][ks] = *(const bf16x8*)&sA[(w * 32 + m * 16 + l15) * 136 + ks * 32 + g * 8];

    // ---- tri bias via MFMA (B-frags from global wtT, L2-hot) ----
    #pragma unroll
    for (int m = 0; m < 2; ++m) {
        f32x4 tc = (f32x4){0.f, 0.f, 0.f, 0.f};
        #pragma unroll
        for (int ks = 0; ks < 4; ++ks) {
            const bf16x8 bfw = *(const bf16x8*)(wtT + l15 * 128 + ks * 32 + g * 8);
            tc = MFMA16(af[m][ks], bfw, tc);
        }
        if (l15 < 4) {
            #pragma unroll
            for (int reg = 0; reg < 4; ++reg) {
                const int gr = rowBase + w * 32 + m * 16 + 4 * g + reg;
                triTb[l15 * 65536 + gr] = (unsigned short)f2bf(tc[reg] * LOG2E);
            }
        }
    }

    // ---- 4 projection GEMMs, K-split halves relayed through registers ----
    for (int mat = 0; mat < 4; ++mat) {
        f32x4 acc[2][8];
        #pragma unroll
        for (int m = 0; m < 2; ++m)
            #pragma unroll
            for (int n = 0; n < 8; ++n) acc[m][n] = (f32x4){0.f, 0.f, 0.f, 0.f};

        // MFMA on kc0 (sB)
        #pragma unroll
        for (int n = 0; n < 8; ++n)
            #pragma unroll
            for (int ks = 0; ks < 2; ++ks) {
                const bf16x8 bf = *(const bf16x8*)&sB[(n * 16 + l15) * 72 + ks * 32 + g * 8];
                acc[0][n] = MFMA16(af[0][ks], bf, acc[0][n]);
                acc[1][n] = MFMA16(af[1][ks], bf, acc[1][n]);
            }
        barrier_lgkm();   // sB(kc0) reads done

        // swap in kc1 from regs; prefetch next mat's kc0
        #pragma unroll
        for (int u = 0; u < 4; ++u)
            *(uint4*)&sB[r2 * 72 + half2 * 32 + u * 8] = wreg[u];
        if (mat < 3) {
            const unsigned short* p = wT + (mat + 1) * 16384 + r2 * 128 + half2 * 32;
            #pragma unroll
            for (int u = 0; u < 4; ++u) wreg[u] = *(const uint4*)(p + u * 8);
        }
        barrier_lgkm();   // sB(kc1) visible

        // MFMA on kc1
        #pragma unroll
        for (int n = 0; n < 8; ++n)
            #pragma unroll
            for (int ks = 0; ks < 2; ++ks) {
                const bf16x8 bf = *(const bf16x8*)&sB[(n * 16 + l15) * 72 + ks * 32 + g * 8];
                acc[0][n] = MFMA16(af[0][2 + ks], bf, acc[0][n]);
                acc[1][n] = MFMA16(af[1][2 + ks], bf, acc[1][n]);
            }
        barrier_lgkm();   // sB(kc1) reads done

        // stage next mat's kc0 from regs; prefetch its kc1; pack -> sA
        if (mat < 3) {
            #pragma unroll
            for (int u = 0; u < 4; ++u)
                *(uint4*)&sB[r2 * 72 + half2 * 32 + u * 8] = wreg[u];
            const unsigned short* p = wT + (mat + 1) * 16384 + r2 * 128 + 64 + half2 * 32;
            #pragma unroll
            for (int u = 0; u < 4; ++u) wreg[u] = *(const uint4*)(p + u * 8);
        }

        float bgv[8];
        if (mat == 3) {
            #pragma unroll
            for (int n = 0; n < 8; ++n) bgv[n] = bg[n * 16 + l15];
        }
        const float scl = (mat == 0) ? 0.25503486245f : 1.0f;   // Ch^-0.5*log2e
        #pragma unroll
        for (int m = 0; m < 2; ++m)
            #pragma unroll
            for (int n = 0; n < 8; ++n) {
                float vv[4];
                #pragma unroll
                for (int reg = 0; reg < 4; ++reg) {
                    float z = acc[m][n][reg];
                    if (mat == 3) z = 1.0f / (1.0f + __expf(-(z + bgv[n])));
                    else z *= scl;
                    vv[reg] = z;
                }
                const unsigned int a01 = cvt_pk_bf16(vv[0], vv[1]);
                const unsigned int a23 = cvt_pk_bf16(vv[2], vv[3]);
                const int qr = w * 32 + m * 16 + g * 4;
                const int col = n * 16 + l15;
                sA[qr * 136 + col]       = (unsigned short)a01;
                sA[(qr + 1) * 136 + col] = (unsigned short)(a01 >> 16);
                sA[(qr + 2) * 136 + col] = (unsigned short)a23;
                sA[(qr + 3) * 136 + col] = (unsigned short)(a23 >> 16);
            }
        barrier_lgkm();   // sA pack + sB stage visible

        // store phase (reads sA; maps identical to r17)
        const int row = rowBase + r2;
        if (mat < 2) {
            unsigned short* dst = (mat == 0) ? qb : kb;
            const int i = row >> 8, j = row & 255;
            #pragma unroll
            for (int u = 0; u < 8; ++u) {
                const int c0 = half2 * 64 + u * 8;
                const int hh = c0 >> 5, ch = c0 & 31;
                *(uint4*)(dst + (((size_t)(i * 4 + hh)) * 256 + j) * 32 + ch) =
                    *(const uint4*)&sA[r2 * 136 + c0];
            }
        } else if (mat == 2) {
            const int c = t & 127, jh = t >> 7;
            const int i = rowBase >> 8;
            const int j0 = (rowBase & 255) + jh * 64;
            unsigned short buf[64];
            #pragma unroll
            for (int u = 0; u < 64; ++u) buf[u] = sA[(jh * 64 + u) * 136 + c];
            unsigned short* dst = vtb + ((size_t)(i * 128 + c)) * 256 + j0;
            #pragma unroll
            for (int u = 0; u < 8; ++u)
                *(uint4*)(dst + u * 8) = *(uint4*)&buf[u * 8];
        } else {
            #pragma unroll
            for (int u = 0; u < 8; ++u) {
                const int c0 = half2 * 64 + u * 8;
                *(uint4*)(gb + (size_t)row * 128 + c0) = *(const uint4*)&sA[r2 * 136 + c0];
            }
        }
        barrier_lgkm();   // sA reads done before next mat's pack
    }
}

// ---------------- Kernel 2: attention (round-17 attn6d, unchanged) --------
__global__ __launch_bounds__(256, 3) void k_attn6d(
    const unsigned short* __restrict__ qb, const unsigned short* __restrict__ kb,
    const unsigned short* __restrict__ vtb, const float* __restrict__ mask,
    const unsigned short* __restrict__ triTb, const unsigned short* __restrict__ gb,
    unsigned short* __restrict__ ob)
{
    __shared__ unsigned short sK[256 * 32];    // [kv][c], 64B rows, XOR-swizzled
    __shared__ unsigned short sVt[32 * 260];   // [ch][kv], pad 260
    __shared__ unsigned short sP[4][64 * 36];  // per-wave [q][32kv+pad]
    __shared__ float sM[256];

    const int i = blockIdx.x, h = blockIdx.y, t = threadIdx.x;
    const int w = t >> 6, lane = t & 63, l15 = lane & 15, g = lane >> 4;
    const size_t base = (size_t)(i * 4 + h) * 8192;

    {
        const uint4* ks = (const uint4*)(kb + base + t * 32);
        char* kdst = (char*)sK + t * 64;
        const int kswz = (t & 3) << 4;
        #pragma unroll
        for (int u = 0; u < 4; ++u)
            *(uint4*)(kdst + ((u * 16) ^ kswz)) = ks[u];

        const int ch = t >> 3, seg = t & 7;
        const uint4* vs = (const uint4*)(vtb + base + (size_t)ch * 256 + seg * 32);
        unsigned short* vdst = &sVt[ch * 260 + seg * 32];
        #pragma unroll
        for (int u = 0; u < 4; ++u)
            *(uint4*)(vdst + u * 8) = vs[u];

        sM[t] = (LOG2E * 1.0e9f) * (mask[i * 256 + t] - 1.0f);
    }

    const int q0 = w * 64;
    bf16x8 qf[4];
    #pragma unroll
    for (int m = 0; m < 4; ++m)
        qf[m] = *(const bf16x8*)(qb + base + (size_t)(q0 + m * 16 + l15) * 32 + g * 8);

    bf16x8 ones;
    #pragma unroll
    for (int u = 0; u < 8; ++u) ones[u] = (short)0x3F80;

    const unsigned short* triQ = triTb + h * 65536;
    ushort4 tbuf[2][4][2];
    #pragma unroll
    for (int m = 0; m < 4; ++m)
        #pragma unroll
        for (int n2 = 0; n2 < 2; ++n2)
            tbuf[0][m][n2] = *(const ushort4*)
                (triQ + (q0 + m * 16 + l15) * 256 + n2 * 16 + g * 4);

    __syncthreads();

    f32x4 acc[4][2], accL[4];
    #pragma unroll
    for (int m = 0; m < 4; ++m) {
        acc[m][0] = (f32x4){0.f, 0.f, 0.f, 0.f};
        acc[m][1] = (f32x4){0.f, 0.f, 0.f, 0.f};
        accL[m]   = (f32x4){0.f, 0.f, 0.f, 0.f};
    }

    unsigned short* sPw = &sP[w][0];

    #pragma unroll
    for (int kt = 0; kt < 4; ++kt) {
        const int kv0 = kt * 64;
        #pragma unroll
        for (int hh = 0; hh < 2; ++hh) {
            const int kvh = kv0 + hh * 32;
            const int s = kt * 2 + hh;
            const int ph = s & 1;

            if (s < 7) {
                const int nkvh = ((s + 1) >> 1) * 64 + ((s + 1) & 1) * 32;
                #pragma unroll
                for (int m = 0; m < 4; ++m)
                    #pragma unroll
                    for (int n2 = 0; n2 < 2; ++n2)
                        tbuf[ph ^ 1][m][n2] = *(const ushort4*)
                            (triQ + (q0 + m * 16 + l15) * 256 + nkvh + n2 * 16 + g * 4);
            }

            bf16x8 kf[2];
            #pragma unroll
            for (int n2 = 0; n2 < 2; ++n2) {
                const int row = kvh + n2 * 16 + l15;
                kf[n2] = *(const bf16x8*)((const char*)sK + row * 64 +
                                          ((g * 16) ^ ((row & 3) << 4)));
            }
            float4 mk[2];
            #pragma unroll
            for (int n2 = 0; n2 < 2; ++n2)
                mk[n2] = *(const float4*)&sM[kvh + n2 * 16 + g * 4];

            #pragma unroll
            for (int m = 0; m < 4; ++m) {
                f32x4 p[2];
                #pragma unroll
                for (int n2 = 0; n2 < 2; ++n2) {
                    const ushort4 tv = tbuf[ph][m][n2];
                    f32x4 cb;
                    cb[0] = mk[n2].x + bf2f(tv.x);
                    cb[1] = mk[n2].y + bf2f(tv.y);
                    cb[2] = mk[n2].z + bf2f(tv.z);
                    cb[3] = mk[n2].w + bf2f(tv.w);
                    p[n2] = MFMA16(kf[n2], qf[m], cb);   // bias folded into C
                }
                #pragma unroll
                for (int n2 = 0; n2 < 2; ++n2) {
                    p[n2][0] = exp2f(p[n2][0]);
                    p[n2][1] = exp2f(p[n2][1]);
                    p[n2][2] = exp2f(p[n2][2]);
                    p[n2][3] = exp2f(p[n2][3]);
                }
                #pragma unroll
                for (int n2 = 0; n2 < 2; ++n2) {
                    const unsigned int a01 = cvt_pk_bf16(p[n2][0], p[n2][1]);
                    const unsigned int a23 = cvt_pk_bf16(p[n2][2], p[n2][3]);
                    *(uint2*)&sPw[(m * 16 + l15) * 36 + n2 * 16 + g * 4] =
                        make_uint2(a01, a23);
                }
            }

            const bf16x8 vf0 = *(const bf16x8*)&sVt[l15 * 260 + kvh + g * 8];
            const bf16x8 vf1 = *(const bf16x8*)&sVt[(16 + l15) * 260 + kvh + g * 8];
            #pragma unroll
            for (int m = 0; m < 4; ++m) {
                const bf16x8 pb = *(const bf16x8*)&sPw[(m * 16 + l15) * 36 + g * 8];
                acc[m][0] = MFMA16(vf0, pb, acc[m][0]);
                acc[m][1] = MFMA16(vf1, pb, acc[m][1]);
                accL[m]   = MFMA16(ones, pb, accL[m]);
            }
        }
    }

    // epilogue: O = (O/l) * gate ; store Oᵀ[ch][q] -> ob[i][q][h][ch]
    #pragma unroll
    for (int m = 0; m < 4; ++m) {
        const float inv = 1.0f / accL[m][0];
        const int q = q0 + m * 16 + l15;
        const unsigned short* gp = gb + (size_t)(i * 256 + q) * 128 + h * 32;
        unsigned short* op = ob + (((size_t)(i * 256 + q)) * 4 + h) * 32;
        #pragma unroll
        for (int n2 = 0; n2 < 2; ++n2) {
            const uint2 gv = *(const uint2*)(gp + n2 * 16 + g * 4);
            const float g0 = bf2f(gv.x & 0xffffu), g1 = bf2f(gv.x >> 16);
            const float g2 = bf2f(gv.y & 0xffffu), g3 = bf2f(gv.y >> 16);
            const unsigned int a01 =
                cvt_pk_bf16(acc[m][n2][0] * inv * g0, acc[m][n2][1] * inv * g1);
            const unsigned int a23 =
                cvt_pk_bf16(acc[m][n2][2] * inv * g2, acc[m][n2][3] * inv * g3);
            *(uint2*)(op + n2 * 16 + g * 4) = make_uint2(a01, a23);
        }
    }
}

// ---------------- Kernel 3: og @ wo + bo (MFMA, K-split) ------------------
__global__ __launch_bounds__(256, 3) void k_out3(
    const unsigned short* __restrict__ ob, const unsigned short* __restrict__ woT,
    const float* __restrict__ bo, float* __restrict__ out)
{
    __shared__ unsigned short sA[128 * 136];
    __shared__ unsigned short sB[128 * 72];
    const int t = threadIdx.x, w = t >> 6, lane = t & 63;
    const int l15 = lane & 15, g = lane >> 4;
    const int rowBase = blockIdx.x * 128;
    const int r = t >> 1, half = t & 1;

    #pragma unroll
    for (int u = 0; u < 8; ++u) {
        const int c = half * 64 + u * 8;
        *(uint4*)&sA[r * 136 + c] = *(const uint4*)(ob + (size_t)(rowBase + r) * 128 + c);
    }

    f32x4 acc[2][8];
    #pragma unroll
    for (int m = 0; m < 2; ++m)
        #pragma unroll
        for (int n = 0; n < 8; ++n) acc[m][n] = (f32x4){0.f, 0.f, 0.f, 0.f};

    #pragma unroll
    for (int kc = 0; kc < 2; ++kc) {
        #pragma unroll
        for (int u = 0; u < 4; ++u)
            *(uint4*)&sB[r * 72 + half * 32 + u * 8] =
                *(const uint4*)(woT + r * 128 + kc * 64 + half * 32 + u * 8);
        __syncthreads();
        #pragma unroll
        for (int ks = 0; ks < 2; ++ks) {
            const bf16x8 a0 = *(const bf16x8*)
                &sA[(w * 32 + l15) * 136 + kc * 64 + ks * 32 + g * 8];
            const bf16x8 a1 = *(const bf16x8*)
                &sA[(w * 32 + 16 + l15) * 136 + kc * 64 + ks * 32 + g * 8];
            #pragma unroll
            for (int n = 0; n < 8; ++n) {
                const bf16x8 bf = *(const bf16x8*)&sB[(n * 16 + l15) * 72 + ks * 32 + g * 8];
                acc[0][n] = MFMA16(a0, bf, acc[0][n]);
                acc[1][n] = MFMA16(a1, bf, acc[1][n]);
            }
        }
        __syncthreads();
    }

    float bov[8];
    #pragma unroll
    for (int n = 0; n < 8; ++n) bov[n] = bo[n * 16 + l15];
    #pragma unroll
    for (int m = 0; m < 2; ++m)
        #pragma unroll
        for (int n = 0; n < 8; ++n)
            #pragma unroll
            for (int reg = 0; reg < 4; ++reg) {
                const int row = rowBase + w * 32 + m * 16 + g * 4 + reg;
                out[(size_t)row * 128 + n * 16 + l15] = acc[m][n][reg] + bov[n];
            }
}

extern "C" void kernel_launch(void* const* d_in, const int* in_sizes, int n_in,
                              void* d_out, int out_size, void* d_ws, size_t ws_size,
                              hipStream_t stream) {
    (void)in_sizes; (void)n_in; (void)out_size; (void)ws_size;
    const float* x     = (const float*)d_in[0];
    const float* mask  = (const float*)d_in[1];
    const float* ln_w  = (const float*)d_in[2];
    const float* ln_b  = (const float*)d_in[3];
    const float* w_tri = (const float*)d_in[4];
    const float* wq    = (const float*)d_in[5];
    const float* wk    = (const float*)d_in[6];
    const float* wv    = (const float*)d_in[7];
    const float* wg    = (const float*)d_in[8];
    const float* bg    = (const float*)d_in[9];
    const float* wo    = (const float*)d_in[10];
    const float* bo    = (const float*)d_in[11];
    float* out = (float*)d_out;

    char* ws = (char*)d_ws;
    unsigned short* qb    = (unsigned short*)(ws + (16u << 20));
    unsigned short* kb    = (unsigned short*)(ws + (32u << 20));
    unsigned short* vtb   = (unsigned short*)(ws + (48u << 20));
    unsigned short* gb    = (unsigned short*)(ws + (64u << 20));
    unsigned short* ob    = (unsigned short*)(ws + (80u << 20));
    unsigned short* triTb = (unsigned short*)(ws + (96u << 20));
    unsigned short* wT    = (unsigned short*)(ws + (97u << 20));
    unsigned short* wtT   = (unsigned short*)(ws + (97u << 20) + 163840);

    k_prep<<<dim3(6, 8), 128, 0, stream>>>(wq, wk, wv, wg, wo, w_tri, wT, wtT);
    k_lnproj<<<512, 256, 0, stream>>>(x, ln_w, ln_b, wtT, wT, bg,
                                      qb, kb, vtb, gb, triTb);
    k_attn6d<<<dim3(256, 4), 256, 0, stream>>>(qb, kb, vtb, mask, triTb, gb, ob);
    k_out3<<<512, 256, 0, stream>>>(ob, wT + 4 * 16384, bo, out);
}

// Round 19
// 100.542 us; speedup vs baseline: 1.1579x; 1.1579x over previous
//
#include <hip/hip_runtime.h>

// Triangle attention, B=1, I=J=256, C=128, H=4, Ch=32.
// Round 19: revert to round-17 (measured best, 100.7us). Round-18's 3-block/CU
// lnproj was the THIRD restructure to trigger L2 partial-writeback
// amplification (WRITE 66->97MB); the r15/r17 phase timing is the only
// measured-clean schedule for this store pattern.
// lnproj: r15 pipeline + lgkm-only barriers. attn6d: tri full-half prefetch,
// bias folded into QK MFMA C. out3: K-split. prep: weight transpose.
// ws layout (bytes):
//   q     bf16 [I][H][J][32]         @ 16 MB   (pre-scaled Ch^-0.5*log2e)
//   k     bf16 [I][H][J][32]         @ 32 MB
//   vt    bf16 [I][H][32(ch)][J]     @ 48 MB
//   g     bf16 [65536][128]          @ 64 MB   (sigmoid gate)
//   o     bf16 [I][J][H][32]         @ 80 MB   (attention out, PRE-GATED)
//   triTb bf16 [H][256(q)][256(kv)]  @ 96 MB   (512 KB, pre-scaled log2e)
//   wT    bf16 5 x [128(n)][128(k)]  @ 97 MB   (160 KB)

typedef __attribute__((ext_vector_type(4))) float f32x4;
typedef __attribute__((ext_vector_type(8))) short bf16x8;
#define MFMA16(a, b, c) __builtin_amdgcn_mfma_f32_16x16x32_bf16(a, b, c, 0, 0, 0)
#define LOG2E 1.4426950408889634f

__device__ __forceinline__ float bf2f(unsigned int u16) {
    return __uint_as_float(u16 << 16);
}
__device__ __forceinline__ unsigned int f2bf(float f) {
    unsigned int u = __float_as_uint(f);
    return (u + 0x7fffu + ((u >> 16) & 1u)) >> 16;
}
__device__ __forceinline__ unsigned int pack2(float a, float b) {
    return f2bf(a) | (f2bf(b) << 16);
}
__device__ __forceinline__ unsigned int cvt_pk_bf16(float lo, float hi) {
    unsigned int r;
    asm("v_cvt_pk_bf16_f32 %0, %1, %2" : "=v"(r) : "v"(lo), "v"(hi));
    return r;
}
// barrier that drains LDS ops only (global stores keep flowing)
__device__ __forceinline__ void barrier_lgkm() {
    asm volatile("s_waitcnt lgkmcnt(0)" ::: "memory");
    __builtin_amdgcn_s_barrier();
}

// ---------------- Kernel 0: weight transpose + bf16 cast ------------------
__global__ __launch_bounds__(128) void k_prep(
    const float* __restrict__ wq, const float* __restrict__ wk,
    const float* __restrict__ wv, const float* __restrict__ wg,
    const float* __restrict__ wo, unsigned short* __restrict__ wT)
{
    const int mat = blockIdx.x, k0 = blockIdx.y * 16, t = threadIdx.x;
    const float* W = (mat == 0) ? wq : (mat == 1) ? wk : (mat == 2) ? wv
                     : (mat == 3) ? wg : wo;
    unsigned short* T = wT + mat * 16384;
    float col[16];
    #pragma unroll
    for (int kk = 0; kk < 16; ++kk) col[kk] = W[(k0 + kk) * 128 + t];
    unsigned int pk[8];
    #pragma unroll
    for (int u = 0; u < 8; ++u) pk[u] = pack2(col[2 * u], col[2 * u + 1]);
    *(uint4*)(T + t * 128 + k0)     = make_uint4(pk[0], pk[1], pk[2], pk[3]);
    *(uint4*)(T + t * 128 + k0 + 8) = make_uint4(pk[4], pk[5], pk[6], pk[7]);
}

// -------- Kernel 1: fused LayerNorm + tri bias + q/k/v/g projections ------
// Round-15 pipelined structure; post-LN barriers are lgkm-only.
__global__ __launch_bounds__(256, 2) void k_lnproj(
    const float* __restrict__ x, const float* __restrict__ ln_w,
    const float* __restrict__ ln_b, const float* __restrict__ w_tri,
    const unsigned short* __restrict__ wT, const float* __restrict__ bg,
    unsigned short* __restrict__ qb, unsigned short* __restrict__ kb,
    unsigned short* __restrict__ vtb, unsigned short* __restrict__ gb,
    unsigned short* __restrict__ triTb)
{
    __shared__ unsigned short sA[128 * 136];   // xn tile, then epilogue bounce
    __shared__ unsigned short sB[128 * 136];   // weights only
    __shared__ unsigned short sWt[16 * 136];   // w_tri^T, rows 4..15 zero

    const int t = threadIdx.x, w = t >> 6, lane = t & 63;
    const int l15 = lane & 15, g = lane >> 4;
    const int rowBase = blockIdx.x * 128;
    const int r2 = t >> 1, half2 = t & 1;

    if (t < 128) {
        const float4 wv = ((const float4*)w_tri)[t];
        sWt[0 * 136 + t] = (unsigned short)f2bf(wv.x);
        sWt[1 * 136 + t] = (unsigned short)f2bf(wv.y);
        sWt[2 * 136 + t] = (unsigned short)f2bf(wv.z);
        sWt[3 * 136 + t] = (unsigned short)f2bf(wv.w);
    } else {
        #pragma unroll
        for (int u = 0; u < 13; ++u) {
            const int idx = (t - 128) + 128 * u;
            if (idx < 12 * 136) sWt[4 * 136 + idx] = 0;
        }
    }

    // ---- LayerNorm: 2 threads per row ----
    {
        const float* xr = x + (size_t)(rowBase + r2) * 128 + half2 * 64;
        float v[64];
        float s1 = 0.0f, s2 = 0.0f;
        #pragma unroll
        for (int u = 0; u < 16; ++u) {
            const float4 q4 = ((const float4*)xr)[u];
            v[4*u] = q4.x; v[4*u+1] = q4.y; v[4*u+2] = q4.z; v[4*u+3] = q4.w;
            s1 += q4.x + q4.y + q4.z + q4.w;
            s2 += q4.x*q4.x + q4.y*q4.y + q4.z*q4.z + q4.w*q4.w;
        }
        s1 += __shfl_xor(s1, 1);
        s2 += __shfl_xor(s2, 1);
        const float mu = s1 * (1.0f / 128.0f);
        const float rs = rsqrtf(s2 * (1.0f / 128.0f) - mu * mu + 1e-5f);
        const float4* lw = (const float4*)(ln_w + half2 * 64);
        const float4* lb = (const float4*)(ln_b + half2 * 64);
        #pragma unroll
        for (int u = 0; u < 16; ++u) {
            const float4 w4 = lw[u], b4 = lb[u];
            v[4*u]   = (v[4*u]   - mu) * rs * w4.x + b4.x;
            v[4*u+1] = (v[4*u+1] - mu) * rs * w4.y + b4.y;
            v[4*u+2] = (v[4*u+2] - mu) * rs * w4.z + b4.z;
            v[4*u+3] = (v[4*u+3] - mu) * rs * w4.w + b4.w;
        }
        #pragma unroll
        for (int u = 0; u < 8; ++u) {
            uint4 pk;
            pk.x = pack2(v[8*u],   v[8*u+1]);
            pk.y = pack2(v[8*u+2], v[8*u+3]);
            pk.z = pack2(v[8*u+4], v[8*u+5]);
            pk.w = pack2(v[8*u+6], v[8*u+7]);
            *(uint4*)&sA[r2 * 136 + half2 * 64 + u * 8] = pk;
        }
    }

    // stage mat-0 weights (latency hidden under LN)
    {
        const unsigned short* Wm = wT + r2 * 128 + half2 * 64;
        #pragma unroll
        for (int u = 0; u < 8; ++u)
            *(uint4*)&sB[r2 * 136 + half2 * 64 + u * 8] = *(const uint4*)(Wm + u * 8);
    }
    __syncthreads();   // full barrier once: sA, sB(w0), sWt ready

    bf16x8 af[2][4];
    #pragma unroll
    for (int m = 0; m < 2; ++m)
        #pragma unroll
        for (int ks = 0; ks < 4; ++ks)
            af[m][ks] = *(const bf16x8*)&sA[(w * 32 + m * 16 + l15) * 136 + ks * 32 + g * 8];

    // ---- tri bias via MFMA (bf16 store, log2e-scaled) ----
    #pragma unroll
    for (int m = 0; m < 2; ++m) {
        f32x4 tc = (f32x4){0.f, 0.f, 0.f, 0.f};
        #pragma unroll
        for (int ks = 0; ks < 4; ++ks) {
            const bf16x8 bfw = *(const bf16x8*)&sWt[l15 * 136 + ks * 32 + g * 8];
            tc = MFMA16(af[m][ks], bfw, tc);
        }
        if (l15 < 4) {
            #pragma unroll
            for (int reg = 0; reg < 4; ++reg) {
                const int gr = rowBase + w * 32 + m * 16 + 4 * g + reg;
                triTb[l15 * 65536 + gr] = (unsigned short)f2bf(tc[reg] * LOG2E);
            }
        }
    }

    // ---- 4 projection GEMMs: MFMA |lgkm| pack->sA |lgkm| stage||store |lgkm|
    for (int mat = 0; mat < 4; ++mat) {
        f32x4 acc[2][8];
        #pragma unroll
        for (int m = 0; m < 2; ++m)
            #pragma unroll
            for (int n = 0; n < 8; ++n) acc[m][n] = (f32x4){0.f, 0.f, 0.f, 0.f};
        #pragma unroll
        for (int n = 0; n < 8; ++n)
            #pragma unroll
            for (int ks = 0; ks < 4; ++ks) {
                const bf16x8 bf = *(const bf16x8*)&sB[(n * 16 + l15) * 136 + ks * 32 + g * 8];
                acc[0][n] = MFMA16(af[0][ks], bf, acc[0][n]);
                acc[1][n] = MFMA16(af[1][ks], bf, acc[1][n]);
            }
        barrier_lgkm();   // sB reads drained (LDS only)

        float bgv[8];
        if (mat == 3) {
            #pragma unroll
            for (int n = 0; n < 8; ++n) bgv[n] = bg[n * 16 + l15];
        }
        const float scl = (mat == 0) ? 0.25503486245f : 1.0f;   // Ch^-0.5*log2e
        #pragma unroll
        for (int m = 0; m < 2; ++m)
            #pragma unroll
            for (int n = 0; n < 8; ++n) {
                float vv[4];
                #pragma unroll
                for (int reg = 0; reg < 4; ++reg) {
                    float z = acc[m][n][reg];
                    if (mat == 3) z = 1.0f / (1.0f + __expf(-(z + bgv[n])));
                    else z *= scl;
                    vv[reg] = z;
                }
                const unsigned int a01 = cvt_pk_bf16(vv[0], vv[1]);
                const unsigned int a23 = cvt_pk_bf16(vv[2], vv[3]);
                const int qr = w * 32 + m * 16 + g * 4;
                const int col = n * 16 + l15;
                sA[qr * 136 + col]       = (unsigned short)a01;
                sA[(qr + 1) * 136 + col] = (unsigned short)(a01 >> 16);
                sA[(qr + 2) * 136 + col] = (unsigned short)a23;
                sA[(qr + 3) * 136 + col] = (unsigned short)(a23 >> 16);
            }
        barrier_lgkm();   // pack visible (LDS only)

        if (mat < 3) {
            const unsigned short* Wm = wT + (mat + 1) * 16384 + r2 * 128 + half2 * 64;
            #pragma unroll
            for (int u = 0; u < 8; ++u)
                *(uint4*)&sB[r2 * 136 + half2 * 64 + u * 8] = *(const uint4*)(Wm + u * 8);
        }

        const int row = rowBase + r2;
        if (mat < 2) {
            unsigned short* dst = (mat == 0) ? qb : kb;
            const int i = row >> 8, j = row & 255;
            #pragma unroll
            for (int u = 0; u < 8; ++u) {
                const int c0 = half2 * 64 + u * 8;
                const int hh = c0 >> 5, ch = c0 & 31;
                *(uint4*)(dst + (((size_t)(i * 4 + hh)) * 256 + j) * 32 + ch) =
                    *(const uint4*)&sA[r2 * 136 + c0];
            }
        } else if (mat == 2) {
            const int c = t & 127, jh = t >> 7;
            const int i = rowBase >> 8;
            const int j0 = (rowBase & 255) + jh * 64;
            unsigned short buf[64];
            #pragma unroll
            for (int u = 0; u < 64; ++u) buf[u] = sA[(jh * 64 + u) * 136 + c];
            unsigned short* dst = vtb + ((size_t)(i * 128 + c)) * 256 + j0;
            #pragma unroll
            for (int u = 0; u < 8; ++u)
                *(uint4*)(dst + u * 8) = *(uint4*)&buf[u * 8];
        } else {
            #pragma unroll
            for (int u = 0; u < 8; ++u) {
                const int c0 = half2 * 64 + u * 8;
                *(uint4*)(gb + (size_t)row * 128 + c0) = *(const uint4*)&sA[r2 * 136 + c0];
            }
        }
        barrier_lgkm();   // sB ds_writes + sA ds_reads drained; global stores flow
    }
}

// ---------------- Kernel 2: attention (tri prefetch + bias-in-C) ----------
__global__ __launch_bounds__(256, 3) void k_attn6d(
    const unsigned short* __restrict__ qb, const unsigned short* __restrict__ kb,
    const unsigned short* __restrict__ vtb, const float* __restrict__ mask,
    const unsigned short* __restrict__ triTb, const unsigned short* __restrict__ gb,
    unsigned short* __restrict__ ob)
{
    __shared__ unsigned short sK[256 * 32];    // [kv][c], 64B rows, XOR-swizzled
    __shared__ unsigned short sVt[32 * 260];   // [ch][kv], pad 260
    __shared__ unsigned short sP[4][64 * 36];  // per-wave [q][32kv+pad]
    __shared__ float sM[256];

    const int i = blockIdx.x, h = blockIdx.y, t = threadIdx.x;
    const int w = t >> 6, lane = t & 63, l15 = lane & 15, g = lane >> 4;
    const size_t base = (size_t)(i * 4 + h) * 8192;

    {
        const uint4* ks = (const uint4*)(kb + base + t * 32);
        char* kdst = (char*)sK + t * 64;
        const int kswz = (t & 3) << 4;
        #pragma unroll
        for (int u = 0; u < 4; ++u)
            *(uint4*)(kdst + ((u * 16) ^ kswz)) = ks[u];

        const int ch = t >> 3, seg = t & 7;
        const uint4* vs = (const uint4*)(vtb + base + (size_t)ch * 256 + seg * 32);
        unsigned short* vdst = &sVt[ch * 260 + seg * 32];
        #pragma unroll
        for (int u = 0; u < 4; ++u)
            *(uint4*)(vdst + u * 8) = vs[u];

        sM[t] = (LOG2E * 1.0e9f) * (mask[i * 256 + t] - 1.0f);
    }

    const int q0 = w * 64;
    bf16x8 qf[4];
    #pragma unroll
    for (int m = 0; m < 4; ++m)
        qf[m] = *(const bf16x8*)(qb + base + (size_t)(q0 + m * 16 + l15) * 32 + g * 8);

    bf16x8 ones;
    #pragma unroll
    for (int u = 0; u < 8; ++u) ones[u] = (short)0x3F80;

    const unsigned short* triQ = triTb + h * 65536;
    ushort4 tbuf[2][4][2];
    #pragma unroll
    for (int m = 0; m < 4; ++m)
        #pragma unroll
        for (int n2 = 0; n2 < 2; ++n2)
            tbuf[0][m][n2] = *(const ushort4*)
                (triQ + (q0 + m * 16 + l15) * 256 + n2 * 16 + g * 4);

    __syncthreads();

    f32x4 acc[4][2], accL[4];
    #pragma unroll
    for (int m = 0; m < 4; ++m) {
        acc[m][0] = (f32x4){0.f, 0.f, 0.f, 0.f};
        acc[m][1] = (f32x4){0.f, 0.f, 0.f, 0.f};
        accL[m]   = (f32x4){0.f, 0.f, 0.f, 0.f};
    }

    unsigned short* sPw = &sP[w][0];

    #pragma unroll
    for (int kt = 0; kt < 4; ++kt) {
        const int kv0 = kt * 64;
        #pragma unroll
        for (int hh = 0; hh < 2; ++hh) {
            const int kvh = kv0 + hh * 32;
            const int s = kt * 2 + hh;
            const int ph = s & 1;

            if (s < 7) {
                const int nkvh = ((s + 1) >> 1) * 64 + ((s + 1) & 1) * 32;
                #pragma unroll
                for (int m = 0; m < 4; ++m)
                    #pragma unroll
                    for (int n2 = 0; n2 < 2; ++n2)
                        tbuf[ph ^ 1][m][n2] = *(const ushort4*)
                            (triQ + (q0 + m * 16 + l15) * 256 + nkvh + n2 * 16 + g * 4);
            }

            bf16x8 kf[2];
            #pragma unroll
            for (int n2 = 0; n2 < 2; ++n2) {
                const int row = kvh + n2 * 16 + l15;
                kf[n2] = *(const bf16x8*)((const char*)sK + row * 64 +
                                          ((g * 16) ^ ((row & 3) << 4)));
            }
            float4 mk[2];
            #pragma unroll
            for (int n2 = 0; n2 < 2; ++n2)
                mk[n2] = *(const float4*)&sM[kvh + n2 * 16 + g * 4];

            #pragma unroll
            for (int m = 0; m < 4; ++m) {
                f32x4 p[2];
                #pragma unroll
                for (int n2 = 0; n2 < 2; ++n2) {
                    const ushort4 tv = tbuf[ph][m][n2];
                    f32x4 cb;
                    cb[0] = mk[n2].x + bf2f(tv.x);
                    cb[1] = mk[n2].y + bf2f(tv.y);
                    cb[2] = mk[n2].z + bf2f(tv.z);
                    cb[3] = mk[n2].w + bf2f(tv.w);
                    p[n2] = MFMA16(kf[n2], qf[m], cb);   // bias folded into C
                }
                #pragma unroll
                for (int n2 = 0; n2 < 2; ++n2) {
                    p[n2][0] = exp2f(p[n2][0]);
                    p[n2][1] = exp2f(p[n2][1]);
                    p[n2][2] = exp2f(p[n2][2]);
                    p[n2][3] = exp2f(p[n2][3]);
                }
                #pragma unroll
                for (int n2 = 0; n2 < 2; ++n2) {
                    const unsigned int a01 = cvt_pk_bf16(p[n2][0], p[n2][1]);
                    const unsigned int a23 = cvt_pk_bf16(p[n2][2], p[n2][3]);
                    *(uint2*)&sPw[(m * 16 + l15) * 36 + n2 * 16 + g * 4] =
                        make_uint2(a01, a23);
                }
            }

            const bf16x8 vf0 = *(const bf16x8*)&sVt[l15 * 260 + kvh + g * 8];
            const bf16x8 vf1 = *(const bf16x8*)&sVt[(16 + l15) * 260 + kvh + g * 8];
            #pragma unroll
            for (int m = 0; m < 4; ++m) {
                const bf16x8 pb = *(const bf16x8*)&sPw[(m * 16 + l15) * 36 + g * 8];
                acc[m][0] = MFMA16(vf0, pb, acc[m][0]);
                acc[m][1] = MFMA16(vf1, pb, acc[m][1]);
                accL[m]   = MFMA16(ones, pb, accL[m]);
            }
        }
    }

    // epilogue: O = (O/l) * gate ; store Oᵀ[ch][q] -> ob[i][q][h][ch]
    #pragma unroll
    for (int m = 0; m < 4; ++m) {
        const float inv = 1.0f / accL[m][0];
        const int q = q0 + m * 16 + l15;
        const unsigned short* gp = gb + (size_t)(i * 256 + q) * 128 + h * 32;
        unsigned short* op = ob + (((size_t)(i * 256 + q)) * 4 + h) * 32;
        #pragma unroll
        for (int n2 = 0; n2 < 2; ++n2) {
            const uint2 gv = *(const uint2*)(gp + n2 * 16 + g * 4);
            const float g0 = bf2f(gv.x & 0xffffu), g1 = bf2f(gv.x >> 16);
            const float g2 = bf2f(gv.y & 0xffffu), g3 = bf2f(gv.y >> 16);
            const unsigned int a01 =
                cvt_pk_bf16(acc[m][n2][0] * inv * g0, acc[m][n2][1] * inv * g1);
            const unsigned int a23 =
                cvt_pk_bf16(acc[m][n2][2] * inv * g2, acc[m][n2][3] * inv * g3);
            *(uint2*)(op + n2 * 16 + g * 4) = make_uint2(a01, a23);
        }
    }
}

// ---------------- Kernel 3: og @ wo + bo (MFMA, K-split) ------------------
__global__ __launch_bounds__(256, 3) void k_out3(
    const unsigned short* __restrict__ ob, const unsigned short* __restrict__ woT,
    const float* __restrict__ bo, float* __restrict__ out)
{
    __shared__ unsigned short sA[128 * 136];
    __shared__ unsigned short sB[128 * 72];
    const int t = threadIdx.x, w = t >> 6, lane = t & 63;
    const int l15 = lane & 15, g = lane >> 4;
    const int rowBase = blockIdx.x * 128;
    const int r = t >> 1, half = t & 1;

    #pragma unroll
    for (int u = 0; u < 8; ++u) {
        const int c = half * 64 + u * 8;
        *(uint4*)&sA[r * 136 + c] = *(const uint4*)(ob + (size_t)(rowBase + r) * 128 + c);
    }

    f32x4 acc[2][8];
    #pragma unroll
    for (int m = 0; m < 2; ++m)
        #pragma unroll
        for (int n = 0; n < 8; ++n) acc[m][n] = (f32x4){0.f, 0.f, 0.f, 0.f};

    #pragma unroll
    for (int kc = 0; kc < 2; ++kc) {
        #pragma unroll
        for (int u = 0; u < 4; ++u)
            *(uint4*)&sB[r * 72 + half * 32 + u * 8] =
                *(const uint4*)(woT + r * 128 + kc * 64 + half * 32 + u * 8);
        __syncthreads();
        #pragma unroll
        for (int ks = 0; ks < 2; ++ks) {
            const bf16x8 a0 = *(const bf16x8*)
                &sA[(w * 32 + l15) * 136 + kc * 64 + ks * 32 + g * 8];
            const bf16x8 a1 = *(const bf16x8*)
                &sA[(w * 32 + 16 + l15) * 136 + kc * 64 + ks * 32 + g * 8];
            #pragma unroll
            for (int n = 0; n < 8; ++n) {
                const bf16x8 bf = *(const bf16x8*)&sB[(n * 16 + l15) * 72 + ks * 32 + g * 8];
                acc[0][n] = MFMA16(a0, bf, acc[0][n]);
                acc[1][n] = MFMA16(a1, bf, acc[1][n]);
            }
        }
        __syncthreads();
    }

    float bov[8];
    #pragma unroll
    for (int n = 0; n < 8; ++n) bov[n] = bo[n * 16 + l15];
    #pragma unroll
    for (int m = 0; m < 2; ++m)
        #pragma unroll
        for (int n = 0; n < 8; ++n)
            #pragma unroll
            for (int reg = 0; reg < 4; ++reg) {
                const int row = rowBase + w * 32 + m * 16 + g * 4 + reg;
                out[(size_t)row * 128 + n * 16 + l15] = acc[m][n][reg] + bov[n];
            }
}

extern "C" void kernel_launch(void* const* d_in, const int* in_sizes, int n_in,
                              void* d_out, int out_size, void* d_ws, size_t ws_size,
                              hipStream_t stream) {
    (void)in_sizes; (void)n_in; (void)out_size; (void)ws_size;
    const float* x     = (const float*)d_in[0];
    const float* mask  = (const float*)d_in[1];
    const float* ln_w  = (const float*)d_in[2];
    const float* ln_b  = (const float*)d_in[3];
    const float* w_tri = (const float*)d_in[4];
    const float* wq    = (const float*)d_in[5];
    const float* wk    = (const float*)d_in[6];
    const float* wv    = (const float*)d_in[7];
    const float* wg    = (const float*)d_in[8];
    const float* bg    = (const float*)d_in[9];
    const float* wo    = (const float*)d_in[10];
    const float* bo    = (const float*)d_in[11];
    float* out = (float*)d_out;

    char* ws = (char*)d_ws;
    unsigned short* qb    = (unsigned short*)(ws + (16u << 20));
    unsigned short* kb    = (unsigned short*)(ws + (32u << 20));
    unsigned short* vtb   = (unsigned short*)(ws + (48u << 20));
    unsigned short* gb    = (unsigned short*)(ws + (64u << 20));
    unsigned short* ob    = (unsigned short*)(ws + (80u << 20));
    unsigned short* triTb = (unsigned short*)(ws + (96u << 20));
    unsigned short* wT    = (unsigned short*)(ws + (97u << 20));

    k_prep<<<dim3(5, 8), 128, 0, stream>>>(wq, wk, wv, wg, wo, wT);
    k_lnproj<<<512, 256, 0, stream>>>(x, ln_w, ln_b, w_tri, wT, bg,
                                      qb, kb, vtb, gb, triTb);
    k_attn6d<<<dim3(256, 4), 256, 0, stream>>>(qb, kb, vtb, mask, triTb, gb, ob);
    k_out3<<<512, 256, 0, stream>>>(ob, wT + 4 * 16384, bo, out);
}